// Round 6
// baseline (179.690 us; speedup 1.0000x reference)
//
#include <hip/hip_runtime.h>
#include <math.h>

// ---------------------------------------------------------------------------
// QFCModel fused: avgpool(6) -> linear(16->4) -> 4-qubit circuit -> linear -> BN
//
// R14: wave-per-sample streaming, max-occupancy design.
// Evidence: R8-R13 all pinned ~175 total; hot kernel ~60us at 760 GB/s with
// occupancy 19% (~6 waves/CU). Hypothesis: per-CU in-flight-read concurrency
// (scales with resident waves) is the staging limit; every prior variant's
// 16-sample/37KB-LDS shape capped waves/CU. This version:
//   * 1 wave = 1 sample; lane l reads <=3 contiguous float4 (144 f4 = rows
//     0-23 x cols 0-23). No LDS staging of x at all.
//   * pooling+encode folded: z_j = sum_px enc_w[j,cell(px)]*x[px]/36, per-lane
//     weighted partials -> 64-lane xor butterfly. No pooled intermediate.
//   * circuit+classifier run redundantly on all lanes (i = lane&15), exactly
//     the R8 math. LDS only V/W2/enc_w (~2.8KB) -> occupancy VGPR-limited
//     (~24 waves/CU, 4x measured R9). 8192 blocks x 4 samples.
// prep/bn kernels unchanged (R13 structure).
// ---------------------------------------------------------------------------

#define BTOT 32768
#define WPB  4                   // waves (=samples) per block
#define NBLK2 (BTOT / WPB)       // 8192 blocks

__device__ float g_prep[576];            // [0:256)=Vr [256:512)=Vi [512:576)=W2
__device__ float g_partials[NBLK2 * 8];  // BN partials (d_ws untouched)

// ---- kernel 1: build V (Vr/Vi, row-major i*16+k) and W2 -------------------
__global__ __launch_bounds__(64) void prep_kernel(
    const float* __restrict__ qparams, const float* __restrict__ cls_w)
{
    const int t = threadIdx.x;
    {   // W2[j][i] = sum_w cls_w[j][w] * sign_w(i)
        int j = t >> 4, i = t & 15;
        float acc = 0.f;
        #pragma unroll
        for (int w = 0; w < 4; ++w)
            acc += cls_w[j * 4 + w] * ((i & (8 >> w)) ? -1.f : 1.f);
        g_prep[512 + j * 16 + i] = acc;
    }
    if (t < 16) {
        // simulate variational layers on basis state e_t -> column t of U
        float pr[16], pi[16];
        #pragma unroll
        for (int i = 0; i < 16; ++i) { pr[i] = (i == t) ? 1.f : 0.f; pi[i] = 0.f; }
        #pragma unroll
        for (int layer = 0; layer < 3; ++layer) {
            #pragma unroll
            for (int w = 0; w < 4; ++w) {
                const float* qp = qparams + (layer * 4 + w) * 3;
                float phi = qp[0], th = qp[1], om = qp[2];
                float c, s, ca, sa, cd, sd;
                __sincosf(0.5f * th, &s, &c);
                __sincosf(0.5f * (phi + om), &sa, &ca);
                __sincosf(0.5f * (phi - om), &sd, &cd);
                float u00r =  c * ca, u00i = -c * sa;
                float u01r = -s * cd, u01i = -s * sd;
                float u10r =  s * cd, u10i = -s * sd;
                float u11r =  c * ca, u11i =  c * sa;
                const int m = 8 >> w;   // wire 0 = MSB
                #pragma unroll
                for (int idx = 0; idx < 16; ++idx) {
                    if (idx & m) continue;
                    const int i1 = idx | m;
                    float ar = pr[idx], ai = pi[idx], br = pr[i1], bi = pi[i1];
                    pr[idx] = u00r*ar - u00i*ai + u01r*br - u01i*bi;
                    pi[idx] = u00r*ai + u00i*ar + u01r*bi + u01i*br;
                    pr[i1]  = u10r*ar - u10i*ai + u11r*br - u11i*bi;
                    pi[i1]  = u10r*ai + u10i*ar + u11r*bi + u11i*br;
                }
            }
            #pragma unroll
            for (int w = 0; w < 3; ++w) {  // CNOT ladder (register renames)
                const int mc = 8 >> w, mt = 8 >> (w + 1);
                #pragma unroll
                for (int idx = 0; idx < 16; ++idx) {
                    if ((idx & mc) && !(idx & mt)) {
                        const int i1 = idx | mt;
                        float tr = pr[idx], ti = pi[idx];
                        pr[idx] = pr[i1]; pi[idx] = pi[i1];
                        pr[i1] = tr;      pi[i1] = ti;
                    }
                }
            }
        }
        // fold (-i)^popcount(column t)
        const int p = __popc(t) & 3;
        #pragma unroll
        for (int i = 0; i < 16; ++i) {
            float re = pr[i], im = pi[i], vr, vi;
            if (p == 0)      { vr = re;  vi = im;  }
            else if (p == 1) { vr = im;  vi = -re; }
            else if (p == 2) { vr = -re; vi = -im; }
            else             { vr = -im; vi = re;  }
            g_prep[i * 16 + t]       = vr;
            g_prep[256 + i * 16 + t] = vi;
        }
    }
}

// ---- kernel 2: wave-per-sample pool+encode+circuit+classify ---------------
__global__ __launch_bounds__(256) void qfc_kernel(
    const float* __restrict__ x,
    const float* __restrict__ enc_w, const float* __restrict__ enc_b,
    const float* __restrict__ cls_b,
    float* __restrict__ preBN)
{
    __shared__ float sVr[16 * 17];       // stride 17: 17k mod 32 injective
    __shared__ float sVi[16 * 17];
    __shared__ float sW2[4 * 17];
    __shared__ float sEw[64];            // enc_w[j][cell], j*16+cell
    __shared__ float red[WPB][8];

    const int tid = threadIdx.x;
    const int l   = tid & 63, wid = tid >> 6;
    const int smp = blockIdx.x * WPB + wid;

    // ---- issue this wave's sample reads first (wave-contiguous 1KB runs) --
    // 144 f4 per sample: o -> (row=o/6, col4=o%6), addr row*7+col4.
    const float4* base4 = (const float4*)(x + (size_t)smp * 784);
    const int o0 = l, o1 = l + 64, o2 = l + 128;
    float4 v0 = base4[(o0 / 6) * 7 + (o0 % 6)];
    float4 v1 = base4[(o1 / 6) * 7 + (o1 % 6)];
    float4 v2 = make_float4(0.f, 0.f, 0.f, 0.f);
    if (l < 16) v2 = base4[(o2 / 6) * 7 + (o2 % 6)];

    // ---- stage tiny tables into LDS (overlaps x-load latency) -------------
    #pragma unroll
    for (int g0 = 0; g0 < 576; g0 += 256) {
        int g = g0 + tid;
        if (g < 576) {
            float v = g_prep[g];
            int row = (g >> 4) & 15, col = g & 15;
            if (g < 256)      sVr[row * 17 + col] = v;
            else if (g < 512) sVi[row * 17 + col] = v;
            else              sW2[(g - 512) / 16 * 17 + col] = v;
        }
    }
    if (tid < 64) sEw[tid] = enc_w[tid];
    __syncthreads();   // sEw needed below; sVr/sVi/sW2 needed after circuit

    // ---- per-lane weighted pool partials: pz_j = sum ew[j,cell]*x ---------
    float pz[4] = {0.f, 0.f, 0.f, 0.f};
    auto FOLD = [&](int o, float4 v) {
        const int c4 = o % 6;          // f4-column within 24-col region
        const int r  = o / 6;          // row 0..23
        const int rb = r / 6;          // row-block 0..3
        const float lo = v.x + v.y, hi = v.z + v.w;
        const int ca = (4 * c4) / 6;   // first cell col
        const bool split = (c4 == 1) | (c4 == 4);
        const float sA = split ? lo : (lo + hi);
        #pragma unroll
        for (int j = 0; j < 4; ++j) {
            float w = sEw[j * 16 + rb * 4 + ca] * sA;
            if (split) w += sEw[j * 16 + rb * 4 + ca + 1] * hi;
            pz[j] += w;
        }
    };
    FOLD(o0, v0);
    FOLD(o1, v1);
    if (l < 16) FOLD(o2, v2);

    // ---- 64-lane butterfly: all lanes get full sums -----------------------
    #pragma unroll
    for (int m = 1; m <= 32; m <<= 1) {
        #pragma unroll
        for (int j = 0; j < 4; ++j) pz[j] += __shfl_xor(pz[j], m, 64);
    }
    float z[4];
    #pragma unroll
    for (int j = 0; j < 4; ++j) z[j] = pz[j] * (1.f / 36.f) + enc_b[j];

    // ---- product state r_k ------------------------------------------------
    float cz[4], sz[4];
    #pragma unroll
    for (int j = 0; j < 4; ++j) __sincosf(0.5f * z[j], &sz[j], &cz[j]);
    float a01[4] = {cz[0]*cz[1], cz[0]*sz[1], sz[0]*cz[1], sz[0]*sz[1]};
    float a23[4] = {cz[2]*cz[3], cz[2]*sz[3], sz[2]*cz[3], sz[2]*sz[3]};
    float rv[16];
    #pragma unroll
    for (int k = 0; k < 16; ++k) rv[k] = a01[k >> 2] * a23[k & 3];

    // ---- matvec row i = l&15 (4x redundant); prob; classifier -------------
    const int i = l & 15;
    float ar = 0.f, ai = 0.f;
    #pragma unroll
    for (int k = 0; k < 16; ++k) {
        ar += sVr[i * 17 + k] * rv[k];
        ai += sVi[i * 17 + k] * rv[k];
    }
    const float prob = ar * ar + ai * ai;
    float out[4];
    #pragma unroll
    for (int j = 0; j < 4; ++j) out[j] = sW2[j * 17 + i] * prob;
    #pragma unroll
    for (int m = 1; m <= 8; m <<= 1) {
        #pragma unroll
        for (int j = 0; j < 4; ++j) out[j] += __shfl_xor(out[j], m, 64);
    }
    #pragma unroll
    for (int j = 0; j < 4; ++j) out[j] += cls_b[j];

    if (l == 0) {
        ((float4*)preBN)[smp] = make_float4(out[0], out[1], out[2], out[3]);
        #pragma unroll
        for (int j = 0; j < 4; ++j) {
            red[wid][j]     = out[j];
            red[wid][4 + j] = out[j] * out[j];
        }
    }
    __syncthreads();
    if (tid < 8) {
        float a = 0.f;
        #pragma unroll
        for (int w = 0; w < WPB; ++w) a += red[w][tid];
        g_partials[blockIdx.x * 8 + tid] = a;
    }
}

// ---- kernel 3: reduce partials (redundantly per block) + batch-norm -------
__global__ __launch_bounds__(256) void bn_kernel(
    const float* __restrict__ gamma, const float* __restrict__ beta,
    float* __restrict__ out)
{
    const int tid = threadIdx.x;
    float acc[8] = {0, 0, 0, 0, 0, 0, 0, 0};
    const float4* p4 = (const float4*)g_partials;
    #pragma unroll
    for (int it = 0; it < NBLK2 / 256; ++it) {
        int b = it * 256 + tid;
        float4 a = p4[b * 2], c = p4[b * 2 + 1];
        acc[0] += a.x; acc[1] += a.y; acc[2] += a.z; acc[3] += a.w;
        acc[4] += c.x; acc[5] += c.y; acc[6] += c.z; acc[7] += c.w;
    }
    #pragma unroll
    for (int off = 32; off >= 1; off >>= 1) {
        #pragma unroll
        for (int m = 0; m < 8; ++m) acc[m] += __shfl_xor(acc[m], off, 64);
    }
    __shared__ float red[4][8];
    const int wave = tid >> 6, lane = tid & 63;
    if (lane == 0) {
        #pragma unroll
        for (int m = 0; m < 8; ++m) red[wave][m] = acc[m];
    }
    __syncthreads();
    float sums[8];
    #pragma unroll
    for (int m = 0; m < 8; ++m)
        sums[m] = red[0][m] + red[1][m] + red[2][m] + red[3][m];

    const int s = blockIdx.x * 256 + tid;
    const float invB = 1.f / (float)BTOT;
    float4 v = ((const float4*)out)[s];
    float o[4] = {v.x, v.y, v.z, v.w};
    #pragma unroll
    for (int j = 0; j < 4; ++j) {
        float mu   = sums[j] * invB;
        float var  = sums[4 + j] * invB - mu * mu;
        float rstd = rsqrtf(var + 1e-5f);
        o[j] = (o[j] - mu) * rstd * gamma[j] + beta[j];
    }
    ((float4*)out)[s] = make_float4(o[0], o[1], o[2], o[3]);
}

extern "C" void kernel_launch(void* const* d_in, const int* in_sizes, int n_in,
                              void* d_out, int out_size, void* d_ws, size_t ws_size,
                              hipStream_t stream)
{
    const float* x        = (const float*)d_in[0];
    const float* enc_w    = (const float*)d_in[1];
    const float* enc_b    = (const float*)d_in[2];
    const float* qparams  = (const float*)d_in[3];
    const float* cls_w    = (const float*)d_in[4];
    const float* cls_b    = (const float*)d_in[5];
    const float* bn_gamma = (const float*)d_in[6];
    const float* bn_beta  = (const float*)d_in[7];

    float* outp = (float*)d_out;     // pre-BN scratch == final out
    (void)d_ws; (void)ws_size;       // ws poison is unconditional (R9 result)

    prep_kernel<<<1, 64, 0, stream>>>(qparams, cls_w);
    qfc_kernel<<<NBLK2, 256, 0, stream>>>(x, enc_w, enc_b, cls_b, outp);
    bn_kernel<<<128, 256, 0, stream>>>(bn_gamma, bn_beta, outp);
}